// Round 9
// baseline (1532.208 us; speedup 1.0000x reference)
//
#include <hip/hip_runtime.h>

// Llama4TextExperts: E=8, H=2048, D=2048, 4096 tokens/expert.
// out = (up * silu(gate)) @ W2,  [gate|up] = x @ W1
// Round 9: r8 structure (128x256, BK=32, 3-deep ring, 2 blocks/CU) +
//  (1) hoisted LDS fragment pointers + K-loop unroll x3 (compile-time ring
//      slot -> ds_read immediate offsets, no per-tile addr VALU),
//  (2) W2-transpose prepass fused into G1's grid (rides G1's spare HBM BW).

#define E_EXPERTS 8
#define TPE 4096
#define KD 2048

typedef __bf16 bf16_t;
typedef __bf16 bf16x4 __attribute__((ext_vector_type(4)));
typedef __bf16 bf16x8 __attribute__((ext_vector_type(8)));
typedef float f32x4 __attribute__((ext_vector_type(4)));

#define GLOAD16(src, dst)                                               \
  __builtin_amdgcn_global_load_lds(                                     \
      (const __attribute__((address_space(1))) void*)(src),             \
      (__attribute__((address_space(3))) void*)(dst), 16, 0, 0)

// ---------------- pass 1: x f32 -> bf16 ----------------
__global__ void cvt_f32_bf16_kernel(const float* __restrict__ in,
                                    bf16_t* __restrict__ out, long n4) {
  long i = (long)blockIdx.x * blockDim.x + threadIdx.x;
  const long stride = (long)gridDim.x * blockDim.x;
  const float4* in4 = (const float4*)in;
  bf16x4* out4 = (bf16x4*)out;
  for (; i < n4; i += stride) {
    float4 v = in4[i];
    bf16x4 o = {(bf16_t)v.x, (bf16_t)v.y, (bf16_t)v.z, (bf16_t)v.w};
    out4[i] = o;
  }
}

// ------- pass 2 (W1 only): transpose+convert W[K][N] f32 -> WT[N][K] bf16 -------
__global__ void transpose_cvt_kernel(const float* __restrict__ W,
                                     bf16_t* __restrict__ WT, int K, int N) {
  __shared__ float tile[64][65];
  const int e = blockIdx.z;
  const float* Wp = W + (size_t)e * K * N;
  bf16_t* Tp = WT + (size_t)e * N * K;
  const int n0 = blockIdx.x * 64, k0 = blockIdx.y * 64;
  const int rr = threadIdx.x >> 4;
  const int cc = (threadIdx.x & 15) * 4;
#pragma unroll
  for (int p = 0; p < 4; ++p) {
    const int k = rr + p * 16;
    float4 v = *(const float4*)(Wp + (size_t)(k0 + k) * N + n0 + cc);
    tile[k][cc + 0] = v.x;
    tile[k][cc + 1] = v.y;
    tile[k][cc + 2] = v.z;
    tile[k][cc + 3] = v.w;
  }
  __syncthreads();
#pragma unroll
  for (int p = 0; p < 4; ++p) {
    const int n = rr + p * 16;
    bf16x4 o;
#pragma unroll
    for (int j = 0; j < 4; ++j) o[j] = (bf16_t)tile[cc + j][n];
    *(bf16x4*)(Tp + (size_t)(n0 + n) * K + k0 + cc) = o;
  }
}

// ---- W2 transpose as a piggyback block inside G1 (512 threads, 2 jobs) ----
// job = e*1024 + ky*32 + nx ; tile 64x64 of W2 [2048][2048] per expert.
__device__ inline void tw2_transpose(const float* __restrict__ W,
                                     bf16_t* __restrict__ WT, int b,
                                     void* lds) {
  float(*tile)[65] = (float(*)[65])lds;  // 16.6 KiB, overlays As region
#pragma unroll 1
  for (int jj = 0; jj < 2; ++jj) {
    const int job = b + jj * 4096;
    const int nx = job & 31, ky = (job >> 5) & 31, e = job >> 10;
    const float* Wp = W + (size_t)e * KD * KD;
    bf16_t* Tp = WT + (size_t)e * KD * KD;
    const int n0 = nx * 64, k0 = ky * 64;
    const int rr = threadIdx.x >> 4;        // 0..31
    const int cc = (threadIdx.x & 15) * 4;  // 0..60
    if (jj) __syncthreads();                // protect tile reuse across jobs
#pragma unroll
    for (int p = 0; p < 2; ++p) {
      const int k = rr + p * 32;
      float4 v = *(const float4*)(Wp + (size_t)(k0 + k) * KD + n0 + cc);
      tile[k][cc + 0] = v.x;
      tile[k][cc + 1] = v.y;
      tile[k][cc + 2] = v.z;
      tile[k][cc + 3] = v.w;
    }
    __syncthreads();
#pragma unroll
    for (int p = 0; p < 2; ++p) {
      const int n = rr + p * 32;
      bf16x4 o;
#pragma unroll
      for (int q = 0; q < 4; ++q) o[q] = (bf16_t)tile[cc + q][n];
      *(bf16x4*)(Tp + (size_t)(n0 + n) * KD + k0 + cc) = o;
    }
  }
}

// ---------------- 128x256 BK=32 2-blocks/CU grouped GEMM ----------------
// Same LDS layout/schedule as round 8 (see its audit). This round: fragment
// LDS addresses hoisted into pA[4]/pB[4]; K-loop unrolled x3 so the ring slot
// is a compile-time constant folded into ds_read immediate offsets.
// TW2: gid%16<8 -> gemm block j=8*(gid/16)+gid%16; else -> tw2 piggyback.
template <bool FUSED, int NTN, bool TW2>
__global__ __launch_bounds__(512, 4) void moe_gemm_tlp_kernel(
    const bf16_t* __restrict__ A, const bf16_t* __restrict__ Bm,
    void* __restrict__ Cout, const float* __restrict__ W2src,
    bf16_t* __restrict__ W2dst) {
  constexpr int NT = KD / 32;  // 64 K-tiles

  __shared__ alignas(16) bf16_t As[3][64][64];    // 24 KiB
  __shared__ alignas(16) bf16_t Bs[3][128][64];   // 48 KiB

  int j;
  if constexpr (TW2) {
    const int x = blockIdx.x & 15, g = blockIdx.x >> 4;
    if (x >= 8) {
      tw2_transpose(W2src, W2dst, 8 * g + (x - 8), (void*)&As[0][0][0]);
      return;
    }
    j = 8 * g + x;
  } else {
    j = blockIdx.x;
  }

  // bijective XCD swizzle over the gemm sub-grid (NWG%8==0); one expert/XCD.
  const int NWG = TW2 ? (gridDim.x >> 1) : gridDim.x;
  int wg = (j & 7) * (NWG >> 3) + (j >> 3);
  const int e = wg / (32 * NTN);
  const int rem = wg % (32 * NTN);
  const int mt = rem / NTN, ntile = rem % NTN;
  const int t0 = mt * 128, n0 = ntile * 256;

  const int tid = threadIdx.x;
  const int wid = tid >> 6, lane = tid & 63;
  const int wr = wid >> 2, wc = wid & 3;  // 2(M) x 4(N); 64x64 per wave

  const bf16_t* Ae = A + (size_t)e * TPE * KD + (size_t)t0 * KD;
  const bf16_t* Be = Bm + (size_t)e * (size_t)(FUSED ? 4096 : 2048) * KD;

  // ---- staging source (per-lane constants; see r8 layout derivation) ----
  const int sp = lane >> 3;  // phys-row offset within 8-row gload
  const int lc = lane & 7;   // written chunk

  const int pAr = wid * 8 + sp;
  const int cAr = lc ^ (pAr & 7);
  const bf16_t* aSrc = Ae + (size_t)(pAr + 64 * (cAr >> 2)) * KD + (cAr & 3) * 8;

  const bf16_t* bSrc[2];
#pragma unroll
  for (int i = 0; i < 2; ++i) {
    const int p = wid * 16 + i * 8 + sp;
    const int c = lc ^ (p & 7);
    const int R = n0 + p + 128 * (c >> 2);
    int srow;
    if constexpr (FUSED)
      srow = ((R >> 5) << 4) + (R & 15) + ((R >> 4) & 1) * 2048;
    else
      srow = R;
    bSrc[i] = Be + (size_t)srow * KD + (c & 3) * 8;
  }

  auto stageA = [&](int kt, int slot) {
    const int k0 = (kt & (NT - 1)) * 32;
    GLOAD16(aSrc + k0, &As[slot][wid * 8][0]);
  };
  auto stageB = [&](int kt, int slot) {
    const int k0 = (kt & (NT - 1)) * 32;
#pragma unroll
    for (int i = 0; i < 2; ++i)
      GLOAD16(bSrc[i] + k0, &Bs[slot][wid * 16 + i * 8][0]);
  };

  // ---- hoisted per-lane fragment addresses (slot 0; slot adds immediate) ----
  const int la = lane & 15, kg4 = lane >> 4;

  const bf16_t* pA[4];
#pragma unroll
  for (int m = 0; m < 4; ++m) {
    const int r = wr * 64 + m * 16 + la;  // [0,128)
    const int p = r & 63, h = r >> 6;
    const int c = (h * 4 + kg4) ^ (p & 7);
    pA[m] = &As[0][p][c * 8];
  }
  const bf16_t* pB[4];
#pragma unroll
  for (int q = 0; q < 2; ++q)
#pragma unroll
    for (int jf = 0; jf < 2; ++jf) {
      const int R = wc * 64 + q * 32 + jf * 16 + la;  // [0,256)
      const int p = R & 127, h = R >> 7;
      const int c = (h * 4 + kg4) ^ (p & 7);
      pB[q * 2 + jf] = &Bs[0][p][c * 8];
    }

  f32x4 acc[4][4] = {};
  bf16x8 am[4];
  bf16x8 bn[2];

#define W0 asm volatile("s_waitcnt lgkmcnt(0)" ::: "memory")
#define VMC3 asm volatile("s_waitcnt vmcnt(3)" ::: "memory")
#define BAR __builtin_amdgcn_s_barrier()
#define SCHED0 __builtin_amdgcn_sched_barrier(0)
#define PRIO1 __builtin_amdgcn_s_setprio(1)
#define PRIO0 __builtin_amdgcn_s_setprio(0)

  // TILE with compile-time ring slot S (reads) and S2 (stage dest = slot of
  // tile t-1; its readers drained pre-BAR). Audit identical to round 8.
#define TILE(t, S, S2)                                                       \
  do {                                                                       \
    am[0] = *(const bf16x8*)(pA[0] + (S) * 4096);                            \
    am[1] = *(const bf16x8*)(pA[1] + (S) * 4096);                            \
    am[2] = *(const bf16x8*)(pA[2] + (S) * 4096);                            \
    am[3] = *(const bf16x8*)(pA[3] + (S) * 4096);                            \
    bn[0] = *(const bf16x8*)(pB[0] + (S) * 8192);                            \
    bn[1] = *(const bf16x8*)(pB[1] + (S) * 8192);                            \
    stageA((t) + 2, S2);                                                     \
    stageB((t) + 2, S2);                                                     \
    W0; SCHED0;                                                              \
    PRIO1;                                                                   \
    _Pragma("unroll") for (int m = 0; m < 4; ++m) {                          \
      acc[m][0] = __builtin_amdgcn_mfma_f32_16x16x32_bf16(am[m], bn[0],      \
                                                          acc[m][0], 0, 0, 0); \
      acc[m][1] = __builtin_amdgcn_mfma_f32_16x16x32_bf16(am[m], bn[1],      \
                                                          acc[m][1], 0, 0, 0); \
    }                                                                        \
    PRIO0;                                                                   \
    bn[0] = *(const bf16x8*)(pB[2] + (S) * 8192);                            \
    bn[1] = *(const bf16x8*)(pB[3] + (S) * 8192);                            \
    W0; SCHED0;                                                              \
    PRIO1;                                                                   \
    _Pragma("unroll") for (int m = 0; m < 4; ++m) {                          \
      acc[m][2] = __builtin_amdgcn_mfma_f32_16x16x32_bf16(am[m], bn[0],      \
                                                          acc[m][2], 0, 0, 0); \
      acc[m][3] = __builtin_amdgcn_mfma_f32_16x16x32_bf16(am[m], bn[1],      \
                                                          acc[m][3], 0, 0, 0); \
    }                                                                        \
    PRIO0;                                                                   \
    VMC3;                                                                    \
    BAR; SCHED0;                                                             \
  } while (0)

  // prologue: tiles 0,1 -> slots 0,1; drain tile0 (keep tile1 in flight)
  stageA(0, 0); stageB(0, 0);
  stageA(1, 1); stageB(1, 1);
  VMC3;
  BAR; SCHED0;

  int t = 0;
  for (; t < NT - 3; t += 3) {  // 21 iterations: tiles 0..62
    TILE(t, 0, 2);
    TILE(t + 1, 1, 0);
    TILE(t + 2, 2, 1);
  }
  TILE(t, 0, 2);  // tile 63 (63%3==0 -> slot 0)

  // Epilogue. C/D layout: row=(lane>>4)*4+r, col=lane&15 (verified).
  const int rbase = t0 + wr * 64;
  if constexpr (FUSED) {
    bf16_t* Cp = (bf16_t*)Cout + (size_t)e * TPE * KD;
    const int jb = (n0 >> 1) + 32 * wc;  // frag 2q=gate, 2q+1=up, same cols
#pragma unroll
    for (int m = 0; m < 4; ++m)
#pragma unroll
      for (int q = 0; q < 2; ++q)
#pragma unroll
        for (int r = 0; r < 4; ++r) {
          const int row = rbase + m * 16 + kg4 * 4 + r;
          const int col = jb + q * 16 + la;
          const float g = acc[m][2 * q][r], u = acc[m][2 * q + 1][r];
          const float sg = 1.0f / (1.0f + __expf(-g));
          Cp[(size_t)row * KD + col] = (bf16_t)(u * g * sg);
        }
  } else {
    float* Cp = (float*)Cout + (size_t)e * TPE * KD;
#pragma unroll
    for (int m = 0; m < 4; ++m)
#pragma unroll
      for (int n = 0; n < 4; ++n)
#pragma unroll
        for (int r = 0; r < 4; ++r) {
          const int row = rbase + m * 16 + kg4 * 4 + r;
          const int col = n0 + wc * 64 + n * 16 + la;
          Cp[(size_t)row * KD + col] = acc[m][n][r];
        }
  }
#undef W0
#undef VMC3
#undef BAR
#undef SCHED0
#undef PRIO1
#undef PRIO0
#undef TILE
}

extern "C" void kernel_launch(void* const* d_in, const int* in_sizes, int n_in,
                              void* d_out, int out_size, void* d_ws,
                              size_t ws_size, hipStream_t stream) {
  const float* hs = (const float*)d_in[0];  // (32768, 2048)
  const float* w1 = (const float*)d_in[1];  // (8, 2048, 4096)
  const float* w2 = (const float*)d_in[2];  // (8, 2048, 2048)

  // ws layout (448 MiB):
  //   xb  bf16 [32768][2048]     128 MiB @ 0
  //   w1t bf16 [8][4096][2048]   128 MiB @ 128M
  //   w2t bf16 [8][2048][2048]    64 MiB @ 256M
  //   act bf16 [8][4096][2048]   128 MiB @ 320M
  char* ws = (char*)d_ws;
  bf16_t* xb = (bf16_t*)(ws);
  bf16_t* w1t = (bf16_t*)(ws + (size_t)134217728);
  bf16_t* w2t = (bf16_t*)(ws + (size_t)268435456);
  bf16_t* act = (bf16_t*)(ws + (size_t)335544320);

  const long n4 = (long)E_EXPERTS * TPE * KD / 4;
  cvt_f32_bf16_kernel<<<2048, 256, 0, stream>>>(hs, xb, n4);
  transpose_cvt_kernel<<<dim3(64, 32, 8), 256, 0, stream>>>(w1, w1t, 2048, 4096);
  // G1 (4096 gemm blocks) + W2-transpose piggyback (4096 blocks x 2 jobs),
  // interleaved at 16-block granularity -> grid 8192.
  moe_gemm_tlp_kernel<true, 16, true>
      <<<8192, 512, 0, stream>>>(xb, w1t, (void*)act, w2, w2t);
  // G2: N=2048 -> NTN=8; grid 8*32*8 = 2048
  moe_gemm_tlp_kernel<false, 8, false>
      <<<2048, 512, 0, stream>>>(act, w2t, d_out, nullptr, nullptr);
}

// Round 10
// 1083.168 us; speedup vs baseline: 1.4146x; 1.4146x over previous
//
#include <hip/hip_runtime.h>

// Llama4TextExperts: E=8, H=2048, D=2048, 4096 tokens/expert.
// out = (up * silu(gate)) @ W2,  [gate|up] = x @ W1
// Round 10: r8 GEMM structure (128x256, BK=32, 3-deep ring, 2 blocks/CU,
// vmcnt(3), 1 barrier/tile) + r9's hoisted LDS fragment pointers / x3 unroll
// (compile-time ring-slot immediates). Prepasses (cvt, W1^T, W2^T) fused into
// ONE streaming kernel, launched BEFORE the GEMMs (r9 showed fusing streaming
// INTO the GEMM thrashes L2: FETCH 594MB->2.2GB).

#define E_EXPERTS 8
#define TPE 4096
#define KD 2048

typedef __bf16 bf16_t;
typedef __bf16 bf16x4 __attribute__((ext_vector_type(4)));
typedef __bf16 bf16x8 __attribute__((ext_vector_type(8)));
typedef float f32x4 __attribute__((ext_vector_type(4)));

#define GLOAD16(src, dst)                                               \
  __builtin_amdgcn_global_load_lds(                                     \
      (const __attribute__((address_space(1))) void*)(src),             \
      (__attribute__((address_space(3))) void*)(dst), 16, 0, 0)

// ---------------- fused prepass: cvt + W1^T + W2^T ----------------
__device__ inline void transpose64(const float* __restrict__ Wp,
                                   bf16_t* __restrict__ Tp, int N, int K,
                                   int n0, int k0, float (*tile)[65]) {
  const int rr = threadIdx.x >> 4;        // 0..15
  const int cc = (threadIdx.x & 15) * 4;  // 0..60
#pragma unroll
  for (int p = 0; p < 4; ++p) {
    const int k = rr + p * 16;
    float4 v = *(const float4*)(Wp + (size_t)(k0 + k) * N + n0 + cc);
    tile[k][cc + 0] = v.x;
    tile[k][cc + 1] = v.y;
    tile[k][cc + 2] = v.z;
    tile[k][cc + 3] = v.w;
  }
  __syncthreads();
#pragma unroll
  for (int p = 0; p < 4; ++p) {
    const int n = rr + p * 16;
    bf16x4 o;
#pragma unroll
    for (int q = 0; q < 4; ++q) o[q] = (bf16_t)tile[cc + q][n];
    *(bf16x4*)(Tp + (size_t)(n0 + n) * K + k0 + cc) = o;
  }
}

// grid: [0,16384) = W1^T tiles; [16384,24576) = W2^T tiles; [24576,26624) cvt.
__global__ __launch_bounds__(256) void prep_kernel(
    const float* __restrict__ hs, bf16_t* __restrict__ xb,
    const float* __restrict__ w1, bf16_t* __restrict__ w1t,
    const float* __restrict__ w2, bf16_t* __restrict__ w2t) {
  __shared__ float tile[64][65];
  const int b = blockIdx.x;
  if (b < 16384) {  // W1 [2048][4096] -> w1t [4096][2048], per expert
    const int nx = b & 63, ky = (b >> 6) & 31, e = b >> 11;
    transpose64(w1 + (size_t)e * KD * 4096, w1t + (size_t)e * 4096 * KD, 4096,
                KD, nx * 64, ky * 64, tile);
  } else if (b < 24576) {  // W2 [2048][2048] -> w2t, per expert
    const int j = b - 16384;
    const int nx = j & 31, ky = (j >> 5) & 31, e = j >> 10;
    transpose64(w2 + (size_t)e * KD * KD, w2t + (size_t)e * KD * KD, KD, KD,
                nx * 64, ky * 64, tile);
  } else {  // cvt: 2048 blocks, grid-stride over 16M float4
    const long n4 = (long)E_EXPERTS * TPE * KD / 4;
    long i = (long)(b - 24576) * blockDim.x + threadIdx.x;
    const long stride = 2048L * 256;
    const float4* in4 = (const float4*)hs;
    bf16x4* out4 = (bf16x4*)xb;
    for (; i < n4; i += stride) {
      float4 v = in4[i];
      bf16x4 o = {(bf16_t)v.x, (bf16_t)v.y, (bf16_t)v.z, (bf16_t)v.w};
      out4[i] = o;
    }
  }
}

// ---------------- 128x256 BK=32 2-blocks/CU grouped GEMM ----------------
// LDS phys layout (A, 128 tile rows): phys row p in [0,64), 128B: logical
// chunk c in [0,8): half h=c>>2, k-octet kg=c&3 -> tile row p+64h, k kg*8..+8.
// Stored at chunk c^(p&7) (involution; same XOR on stage-source and read).
// B: 256 tile rows -> 128 phys rows, h = R>>7.
// Waves 2(M)x4(N), 64x64 per wave. Per K-tile t (slot s=t%3, dest s2=(s+2)%3
// = slot of t-1 whose readers drained at (t-1).P2 W0, sealed by its BAR):
//  P1: ds_read A(4)+B(2) [hoisted ptrs + slot immediates]; stage t+2 (3
//      gloads); W0; 8 MFMA.   P2: ds_read B(2); W0; 8 MFMA; VMC3; BAR.
// vmcnt audit: at P2 end outstanding={t+1(3),t+2(3)}; VMC3 keeps t+2 -> t+1
// landed before t+1.P1 reads (sealed by BAR).
template <bool FUSED, int NTN>
__global__ __launch_bounds__(512, 4) void moe_gemm_tlp_kernel(
    const bf16_t* __restrict__ A, const bf16_t* __restrict__ Bm,
    void* __restrict__ Cout) {
  constexpr int NT = KD / 32;  // 64 K-tiles

  __shared__ alignas(16) bf16_t As[3][64][64];    // 24 KiB
  __shared__ alignas(16) bf16_t Bs[3][128][64];   // 48 KiB

  // bijective XCD swizzle (grid%8==0): one expert per XCD; intra-XCD
  // row-major (A-panel shared by consecutive blocks).
  const int NWG = gridDim.x;
  int wg = blockIdx.x;
  wg = (wg & 7) * (NWG >> 3) + (wg >> 3);
  const int e = wg / (32 * NTN);
  const int rem = wg % (32 * NTN);
  const int mt = rem / NTN, ntile = rem % NTN;
  const int t0 = mt * 128, n0 = ntile * 256;

  const int tid = threadIdx.x;
  const int wid = tid >> 6, lane = tid & 63;
  const int wr = wid >> 2, wc = wid & 3;  // 2(M) x 4(N); 64x64 per wave

  const bf16_t* Ae = A + (size_t)e * TPE * KD + (size_t)t0 * KD;
  const bf16_t* Be = Bm + (size_t)e * (size_t)(FUSED ? 4096 : 2048) * KD;

  // ---- staging source (per-lane constants; see layout derivation above) ----
  const int sp = lane >> 3;  // phys-row offset within 8-row gload
  const int lc = lane & 7;   // written chunk

  const int pAr = wid * 8 + sp;
  const int cAr = lc ^ (pAr & 7);
  const bf16_t* aSrc = Ae + (size_t)(pAr + 64 * (cAr >> 2)) * KD + (cAr & 3) * 8;

  const bf16_t* bSrc[2];
#pragma unroll
  for (int i = 0; i < 2; ++i) {
    const int p = wid * 16 + i * 8 + sp;
    const int c = lc ^ (p & 7);
    const int R = n0 + p + 128 * (c >> 2);
    int srow;
    if constexpr (FUSED)
      srow = ((R >> 5) << 4) + (R & 15) + ((R >> 4) & 1) * 2048;
    else
      srow = R;
    bSrc[i] = Be + (size_t)srow * KD + (c & 3) * 8;
  }

  auto stageA = [&](int kt, int slot) {
    const int k0 = (kt & (NT - 1)) * 32;
    GLOAD16(aSrc + k0, &As[slot][wid * 8][0]);
  };
  auto stageB = [&](int kt, int slot) {
    const int k0 = (kt & (NT - 1)) * 32;
#pragma unroll
    for (int i = 0; i < 2; ++i)
      GLOAD16(bSrc[i] + k0, &Bs[slot][wid * 16 + i * 8][0]);
  };

  // ---- hoisted per-lane fragment addresses (slot 0; +slot immediate) ----
  const int la = lane & 15, kg4 = lane >> 4;

  const bf16_t* pA[4];
#pragma unroll
  for (int m = 0; m < 4; ++m) {
    const int r = wr * 64 + m * 16 + la;  // [0,128)
    const int p = r & 63, h = r >> 6;
    const int c = (h * 4 + kg4) ^ (p & 7);
    pA[m] = &As[0][p][c * 8];
  }
  const bf16_t* pB[4];
#pragma unroll
  for (int q = 0; q < 2; ++q)
#pragma unroll
    for (int jf = 0; jf < 2; ++jf) {
      const int R = wc * 64 + q * 32 + jf * 16 + la;  // [0,256)
      const int p = R & 127, h = R >> 7;
      const int c = (h * 4 + kg4) ^ (p & 7);
      pB[q * 2 + jf] = &Bs[0][p][c * 8];
    }

  f32x4 acc[4][4] = {};
  bf16x8 am[4];
  bf16x8 bn[2];

#define W0 asm volatile("s_waitcnt lgkmcnt(0)" ::: "memory")
#define VMC3 asm volatile("s_waitcnt vmcnt(3)" ::: "memory")
#define BAR __builtin_amdgcn_s_barrier()
#define SCHED0 __builtin_amdgcn_sched_barrier(0)
#define PRIO1 __builtin_amdgcn_s_setprio(1)
#define PRIO0 __builtin_amdgcn_s_setprio(0)

#define TILE(t, S, S2)                                                       \
  do {                                                                       \
    am[0] = *(const bf16x8*)(pA[0] + (S) * 4096);                            \
    am[1] = *(const bf16x8*)(pA[1] + (S) * 4096);                            \
    am[2] = *(const bf16x8*)(pA[2] + (S) * 4096);                            \
    am[3] = *(const bf16x8*)(pA[3] + (S) * 4096);                            \
    bn[0] = *(const bf16x8*)(pB[0] + (S) * 8192);                            \
    bn[1] = *(const bf16x8*)(pB[1] + (S) * 8192);                            \
    stageA((t) + 2, S2);                                                     \
    stageB((t) + 2, S2);                                                     \
    W0; SCHED0;                                                              \
    PRIO1;                                                                   \
    _Pragma("unroll") for (int m = 0; m < 4; ++m) {                          \
      acc[m][0] = __builtin_amdgcn_mfma_f32_16x16x32_bf16(am[m], bn[0],      \
                                                          acc[m][0], 0, 0, 0); \
      acc[m][1] = __builtin_amdgcn_mfma_f32_16x16x32_bf16(am[m], bn[1],      \
                                                          acc[m][1], 0, 0, 0); \
    }                                                                        \
    PRIO0;                                                                   \
    bn[0] = *(const bf16x8*)(pB[2] + (S) * 8192);                            \
    bn[1] = *(const bf16x8*)(pB[3] + (S) * 8192);                            \
    W0; SCHED0;                                                              \
    PRIO1;                                                                   \
    _Pragma("unroll") for (int m = 0; m < 4; ++m) {                          \
      acc[m][2] = __builtin_amdgcn_mfma_f32_16x16x32_bf16(am[m], bn[0],      \
                                                          acc[m][2], 0, 0, 0); \
      acc[m][3] = __builtin_amdgcn_mfma_f32_16x16x32_bf16(am[m], bn[1],      \
                                                          acc[m][3], 0, 0, 0); \
    }                                                                        \
    PRIO0;                                                                   \
    VMC3;                                                                    \
    BAR; SCHED0;                                                             \
  } while (0)

  // prologue: tiles 0,1 -> slots 0,1; drain tile0 (keep tile1 in flight)
  stageA(0, 0); stageB(0, 0);
  stageA(1, 1); stageB(1, 1);
  VMC3;
  BAR; SCHED0;

  int t = 0;
  for (; t < NT - 3; t += 3) {  // 21 iterations: tiles 0..62
    TILE(t, 0, 2);
    TILE(t + 1, 1, 0);
    TILE(t + 2, 2, 1);
  }
  TILE(t, 0, 2);  // tile 63 (63%3==0 -> slot 0)

  // Epilogue. C/D layout: row=(lane>>4)*4+r, col=lane&15 (verified).
  const int rbase = t0 + wr * 64;
  if constexpr (FUSED) {
    bf16_t* Cp = (bf16_t*)Cout + (size_t)e * TPE * KD;
    const int jb = (n0 >> 1) + 32 * wc;  // frag 2q=gate, 2q+1=up, same cols
#pragma unroll
    for (int m = 0; m < 4; ++m)
#pragma unroll
      for (int q = 0; q < 2; ++q)
#pragma unroll
        for (int r = 0; r < 4; ++r) {
          const int row = rbase + m * 16 + kg4 * 4 + r;
          const int col = jb + q * 16 + la;
          const float g = acc[m][2 * q][r], u = acc[m][2 * q + 1][r];
          const float sg = 1.0f / (1.0f + __expf(-g));
          Cp[(size_t)row * KD + col] = (bf16_t)(u * g * sg);
        }
  } else {
    float* Cp = (float*)Cout + (size_t)e * TPE * KD;
#pragma unroll
    for (int m = 0; m < 4; ++m)
#pragma unroll
      for (int n = 0; n < 4; ++n)
#pragma unroll
        for (int r = 0; r < 4; ++r) {
          const int row = rbase + m * 16 + kg4 * 4 + r;
          const int col = n0 + wc * 64 + n * 16 + la;
          Cp[(size_t)row * KD + col] = acc[m][n][r];
        }
  }
#undef W0
#undef VMC3
#undef BAR
#undef SCHED0
#undef PRIO1
#undef PRIO0
#undef TILE
}

extern "C" void kernel_launch(void* const* d_in, const int* in_sizes, int n_in,
                              void* d_out, int out_size, void* d_ws,
                              size_t ws_size, hipStream_t stream) {
  const float* hs = (const float*)d_in[0];  // (32768, 2048)
  const float* w1 = (const float*)d_in[1];  // (8, 2048, 4096)
  const float* w2 = (const float*)d_in[2];  // (8, 2048, 2048)

  // ws layout (448 MiB):
  //   xb  bf16 [32768][2048]     128 MiB @ 0
  //   w1t bf16 [8][4096][2048]   128 MiB @ 128M
  //   w2t bf16 [8][2048][2048]    64 MiB @ 256M
  //   act bf16 [8][4096][2048]   128 MiB @ 320M
  char* ws = (char*)d_ws;
  bf16_t* xb = (bf16_t*)(ws);
  bf16_t* w1t = (bf16_t*)(ws + (size_t)134217728);
  bf16_t* w2t = (bf16_t*)(ws + (size_t)268435456);
  bf16_t* act = (bf16_t*)(ws + (size_t)335544320);

  // fused prepass: W1^T (16384) + W2^T (8192) + cvt (2048) = 26624 blocks
  prep_kernel<<<26624, 256, 0, stream>>>(hs, xb, w1, w1t, w2, w2t);
  // G1: virtual N=4096 -> NTN=16; grid 8*32*16 = 4096
  moe_gemm_tlp_kernel<true, 16><<<4096, 512, 0, stream>>>(xb, w1t, (void*)act);
  // G2: N=2048 -> NTN=8; grid 8*32*8 = 2048
  moe_gemm_tlp_kernel<false, 8><<<2048, 512, 0, stream>>>(act, w2t, d_out);
}